// Round 1
// baseline (489.872 us; speedup 1.0000x reference)
//
#include <hip/hip_runtime.h>
#include <hip/hip_bf16.h>

// Problem constants
#define BROWS 131072
#define GN 28
// ws layout (u16 elements): W1T_hi [28][64][64] | W1T_lo | W2T_hi [28][32][64] | W2T_lo
#define W1T_ELEMS (28*64*64)   // 114688
#define W2T_ELEMS (28*32*64)   // 57344
#define WS_BYTES ((W1T_ELEMS*2 + W2T_ELEMS*2) * 2)  // 688128

typedef __attribute__((ext_vector_type(4))) float f32x4;
typedef __attribute__((ext_vector_type(8))) short short8;
typedef __bf16 bf16x8 __attribute__((ext_vector_type(8)));

__device__ __forceinline__ unsigned short f2bf(float v){
  __hip_bfloat16 h = __float2bfloat16(v);   // RNE
  return __builtin_bit_cast(unsigned short, h);
}
__device__ __forceinline__ float bf2f(unsigned short u){
  unsigned int w = ((unsigned int)u) << 16;
  return __builtin_bit_cast(float, w);
}
__device__ __forceinline__ f32x4 mfma16(short8 a, short8 b, f32x4 c){
  return __builtin_amdgcn_mfma_f32_16x16x32_bf16(
      __builtin_bit_cast(bf16x8, a), __builtin_bit_cast(bf16x8, b), c, 0, 0, 0);
}

// ---------------------------------------------------------------------------
// Prologue: split fp32 weights into bf16 hi/lo, transposed to [n][k] (K-contig)
// W1 in:  [g][k=64][n=64]  -> W1T [g][n=64][k=64]
// W2 in:  [g][k=64][n=32]  -> W2T [g][n=32][k=64]
// One thread per k-PAIR so hi/lo land as single u32 stores.
// 57344 + 28672 = 86016 threads = 336 blocks x 256.
// ---------------------------------------------------------------------------
__global__ void split_weights(const float* __restrict__ W1,
                              const float* __restrict__ W2,
                              unsigned short* __restrict__ ws){
  int t = blockIdx.x * 256 + threadIdx.x;
  unsigned short* w1h = ws;
  unsigned short* w1l = ws + W1T_ELEMS;
  unsigned short* w2h = ws + 2*W1T_ELEMS;
  unsigned short* w2l = ws + 2*W1T_ELEMS + W2T_ELEMS;
  float v0, v1; unsigned short* ph; unsigned short* pl; int o;
  if (t < 57344){                       // W1 pairs: g(28) x n(64) x k2(32)
    int g = t >> 11, rem = t & 2047, n = rem >> 5, k2 = rem & 31;
    v0 = W1[(g*64 + 2*k2    )*64 + n];
    v1 = W1[(g*64 + 2*k2 + 1)*64 + n];
    o  = (g*64 + n)*64 + 2*k2;
    ph = w1h; pl = w1l;
  } else {                              // W2 pairs: g(28) x n(32) x k2(32)
    int t2 = t - 57344;
    int g = t2 >> 10, rem = t2 & 1023, n = rem >> 5, k2 = rem & 31;
    v0 = W2[(g*64 + 2*k2    )*32 + n];
    v1 = W2[(g*64 + 2*k2 + 1)*32 + n];
    o  = (g*32 + n)*64 + 2*k2;
    ph = w2h; pl = w2l;
  }
  unsigned short h0 = f2bf(v0), h1 = f2bf(v1);
  unsigned short l0 = f2bf(v0 - bf2f(h0)), l1 = f2bf(v1 - bf2f(h1));
  *(unsigned int*)(ph + o) = (unsigned)h0 | ((unsigned)h1 << 16);
  *(unsigned int*)(pl + o) = (unsigned)l0 | ((unsigned)l1 << 16);
}

// ---------------------------------------------------------------------------
// Main fused kernel. 1024 blocks x 256 threads (4 waves).
// Block owns 128 rows; wave owns 32 rows; loops all 28 branches.
// Transposed formulation: h1T = W1T·x, h2T = W2T·h1 so both operands are
// K-contiguous. x B-frags held in registers across all branches.
// ---------------------------------------------------------------------------
__global__ __launch_bounds__(256, 2) void mlp_fused(
    const float* __restrict__ x,  const float* __restrict__ b1,
    const float* __restrict__ b2, const float* __restrict__ W3,
    const float* __restrict__ b3, const unsigned short* __restrict__ ws,
    float* __restrict__ out){
  const unsigned short* w1h = ws;
  const unsigned short* w1l = ws + W1T_ELEMS;
  const unsigned short* w2h = ws + 2*W1T_ELEMS;
  const unsigned short* w2l = ws + 2*W1T_ELEMS + W2T_ELEMS;

  // per-wave h1 staging: [wave][hi/lo][r=32][n=64] bf16, XOR-swizzled. 32 KiB.
  __shared__ unsigned int h1s[4][2][1024];
  __shared__ float outb[128*28];                      // 14 KiB

  const int tid = threadIdx.x;
  const int wv  = tid >> 6;
  const int ln  = tid & 63;
  const int l15 = ln & 15;
  const int q   = ln >> 4;
  const int rowBase = blockIdx.x * 128 + wv * 32;

  // ---- x B-fragments (bf16 hi/lo), loaded once, reused for all 28 g ----
  short8 xh[2][2], xl[2][2];
  #pragma unroll
  for (int rt = 0; rt < 2; ++rt)
    #pragma unroll
    for (int ks = 0; ks < 2; ++ks){
      const float* p = x + (rowBase + rt*16 + l15)*64 + ks*32 + q*8;
      f32x4 a = *(const f32x4*)p;
      f32x4 b = *(const f32x4*)(p + 4);
      short8 sh, sl;
      #pragma unroll
      for (int j = 0; j < 4; ++j){
        unsigned short h = f2bf(a[j]);
        sh[j]   = (short)h; sl[j]   = (short)f2bf(a[j] - bf2f(h));
        unsigned short h2 = f2bf(b[j]);
        sh[4+j] = (short)h2; sl[4+j] = (short)f2bf(b[j] - bf2f(h2));
      }
      xh[rt][ks] = sh; xl[rt][ks] = sl;
    }

  char* h1hb = (char*)&h1s[wv][0][0];
  char* h1lb = (char*)&h1s[wv][1][0];

  for (int g = 0; g < GN; ++g){
    // ---------------- layer 1: h1T[n=64][r=32/wave] ----------------
    short8 a1h[4][2], a1l[4][2];
    #pragma unroll
    for (int nt = 0; nt < 4; ++nt)
      #pragma unroll
      for (int ks = 0; ks < 2; ++ks){
        int off = (g*64 + nt*16 + l15)*64 + ks*32 + q*8;
        a1h[nt][ks] = *(const short8*)(w1h + off);
        a1l[nt][ks] = *(const short8*)(w1l + off);
      }
    f32x4 acc1[4][2];
    #pragma unroll
    for (int nt = 0; nt < 4; ++nt){
      f32x4 bias = *(const f32x4*)(b1 + g*64 + nt*16 + q*4);
      acc1[nt][0] = bias; acc1[nt][1] = bias;
    }
    #pragma unroll
    for (int nt = 0; nt < 4; ++nt)
      #pragma unroll
      for (int rt = 0; rt < 2; ++rt)
        #pragma unroll
        for (int ks = 0; ks < 2; ++ks){
          acc1[nt][rt] = mfma16(a1h[nt][ks], xh[rt][ks], acc1[nt][rt]);
          acc1[nt][rt] = mfma16(a1h[nt][ks], xl[rt][ks], acc1[nt][rt]);
          acc1[nt][rt] = mfma16(a1l[nt][ks], xh[rt][ks], acc1[nt][rt]);
        }
    // ---- relu + hi/lo split + packed store to h1s[r][n] (swizzled) ----
    #pragma unroll
    for (int nt = 0; nt < 4; ++nt)
      #pragma unroll
      for (int rt = 0; rt < 2; ++rt){
        f32x4 v = acc1[nt][rt];
        unsigned short h[4], l[4];
        #pragma unroll
        for (int i = 0; i < 4; ++i){
          float vi = fmaxf(v[i], 0.0f);
          h[i] = f2bf(vi); l[i] = f2bf(vi - bf2f(h[i]));
        }
        int r  = rt*16 + l15;
        int n0 = nt*16 + q*4;
        int off = ((r*64 + n0)*2) ^ ((r & 7) << 4);
        uint2 ph = make_uint2((unsigned)h[0] | ((unsigned)h[1] << 16),
                              (unsigned)h[2] | ((unsigned)h[3] << 16));
        uint2 pl = make_uint2((unsigned)l[0] | ((unsigned)l[1] << 16),
                              (unsigned)l[2] | ((unsigned)l[3] << 16));
        *(uint2*)(h1hb + off) = ph;
        *(uint2*)(h1lb + off) = pl;
      }
    // ---------------- layer 2: h2T[n=32][r=32/wave] ----------------
    short8 a2h[2][2], a2l[2][2];
    #pragma unroll
    for (int nt = 0; nt < 2; ++nt)
      #pragma unroll
      for (int ks = 0; ks < 2; ++ks){
        int off = (g*32 + nt*16 + l15)*64 + ks*32 + q*8;
        a2h[nt][ks] = *(const short8*)(w2h + off);
        a2l[nt][ks] = *(const short8*)(w2l + off);
      }
    short8 bh[2][2], bl[2][2];
    #pragma unroll
    for (int rt = 0; rt < 2; ++rt)
      #pragma unroll
      for (int ks = 0; ks < 2; ++ks){
        int r = rt*16 + l15;
        int n = ks*32 + q*8;
        int off = ((r*64 + n)*2) ^ ((r & 7) << 4);
        bh[rt][ks] = __builtin_bit_cast(short8, *(const uint4*)(h1hb + off));
        bl[rt][ks] = __builtin_bit_cast(short8, *(const uint4*)(h1lb + off));
      }
    f32x4 acc2[2][2];
    #pragma unroll
    for (int nt = 0; nt < 2; ++nt){
      f32x4 bias = *(const f32x4*)(b2 + g*32 + nt*16 + q*4);
      acc2[nt][0] = bias; acc2[nt][1] = bias;
    }
    #pragma unroll
    for (int nt = 0; nt < 2; ++nt)
      #pragma unroll
      for (int rt = 0; rt < 2; ++rt)
        #pragma unroll
        for (int ks = 0; ks < 2; ++ks){
          acc2[nt][rt] = mfma16(a2h[nt][ks], bh[rt][ks], acc2[nt][rt]);
          acc2[nt][rt] = mfma16(a2h[nt][ks], bl[rt][ks], acc2[nt][rt]);
          acc2[nt][rt] = mfma16(a2l[nt][ks], bh[rt][ks], acc2[nt][rt]);
        }
    // ---------------- layer 3: in-register dot + quarter-reduce ----------------
    f32x4 w3f[2];
    #pragma unroll
    for (int nt = 0; nt < 2; ++nt)
      w3f[nt] = *(const f32x4*)(W3 + g*32 + nt*16 + q*4);
    float bias3 = b3[g];
    #pragma unroll
    for (int rt = 0; rt < 2; ++rt){
      float p = 0.0f;
      #pragma unroll
      for (int nt = 0; nt < 2; ++nt)
        #pragma unroll
        for (int i = 0; i < 4; ++i)
          p = fmaf(fmaxf(acc2[nt][rt][i], 0.0f), w3f[nt][i], p);
      p += __shfl_xor(p, 16);
      p += __shfl_xor(p, 32);
      p += bias3;
      if (ln < 16)
        outb[(wv*32 + rt*16 + ln)*28 + g] = p;
    }
  }
  __syncthreads();
  // coalesced writeout: out is [B][28] row-major -> block chunk is contiguous
  const int ob = blockIdx.x * (128*28);
  #pragma unroll
  for (int j = 0; j < 14; ++j){
    int idx = j*256 + tid;
    out[ob + idx] = outb[idx];
  }
}

extern "C" void kernel_launch(void* const* d_in, const int* in_sizes, int n_in,
                              void* d_out, int out_size, void* d_ws, size_t ws_size,
                              hipStream_t stream){
  const float* x  = (const float*)d_in[0];
  const float* W1 = (const float*)d_in[1];
  const float* b1 = (const float*)d_in[2];
  const float* W2 = (const float*)d_in[3];
  const float* b2 = (const float*)d_in[4];
  const float* W3 = (const float*)d_in[5];
  const float* b3 = (const float*)d_in[6];
  unsigned short* ws = (unsigned short*)d_ws;
  float* out = (float*)d_out;
  if (ws_size < (size_t)WS_BYTES) return;  // need 672 KiB scratch; fail loud-ish
  hipLaunchKernelGGL(split_weights, dim3(336), dim3(256), 0, stream, W1, W2, ws);
  hipLaunchKernelGGL(mlp_fused, dim3(1024), dim3(256), 0, stream,
                     x, b1, b2, W3, b3, ws, out);
}

// Round 2
// 214.612 us; speedup vs baseline: 2.2826x; 2.2826x over previous
//
#include <hip/hip_runtime.h>
#include <hip/hip_bf16.h>

// Problem constants
#define BROWS 131072
#define GN 28
// ws layout: per-g contiguous 24576-byte tile, pre-swizzled for LDS staging:
//   [ W1h 8KiB | W1l 8KiB | W2h 4KiB | W2l 4KiB ]
// W1 tiles: [n=64][k=64] bf16, byte = n*128 + 2k, XOR-swizzled ^((n&7)<<4)
// W2 tiles: [n2=32][kk=64] bf16 with K-PERMUTATION kk -> kn (see below), same swizzle
#define G_TILE_BYTES 24576
#define WS_BYTES (GN * G_TILE_BYTES)   // 688128

typedef __attribute__((ext_vector_type(4))) float f32x4;
typedef __attribute__((ext_vector_type(8))) short short8;
typedef __bf16 bf16x8 __attribute__((ext_vector_type(8)));

__device__ __forceinline__ unsigned short f2bf(float v){
  __hip_bfloat16 h = __float2bfloat16(v);   // RNE
  return __builtin_bit_cast(unsigned short, h);
}
__device__ __forceinline__ float bf2f(unsigned short u){
  unsigned int w = ((unsigned int)u) << 16;
  return __builtin_bit_cast(float, w);
}
__device__ __forceinline__ f32x4 mfma16(short8 a, short8 b, f32x4 c){
  return __builtin_amdgcn_mfma_f32_16x16x32_bf16(
      __builtin_bit_cast(bf16x8, a), __builtin_bit_cast(bf16x8, b), c, 0, 0, 0);
}

// ---------------------------------------------------------------------------
// Prologue: fp32 weights -> bf16 hi/lo, transposed, pre-swizzled, per-g tiles.
// W2 additionally K-permuted so layer-1 D-fragments feed layer-2 B directly:
//   MFMA k-slot kk = ks*32 + q*8 + u*4 + i  carries  kn = 32*ks + 16*u + 4*q + i
// ---------------------------------------------------------------------------
__global__ void split_weights(const float* __restrict__ W1,
                              const float* __restrict__ W2,
                              unsigned char* __restrict__ ws){
  int t = blockIdx.x * 256 + threadIdx.x;
  if (t < 57344){                       // W1: g(28) x n(64) x m(32)  (m = k-pair)
    int g = t >> 11, rem = t & 2047, n = rem >> 5, m = rem & 31;
    float v0 = W1[(g*64 + 2*m    )*64 + n];
    float v1 = W1[(g*64 + 2*m + 1)*64 + n];
    unsigned short h0 = f2bf(v0), h1 = f2bf(v1);
    unsigned short l0 = f2bf(v0 - bf2f(h0)), l1 = f2bf(v1 - bf2f(h1));
    int off = (n*128 + 4*m) ^ ((n & 7) << 4);
    unsigned char* base = ws + g*G_TILE_BYTES;
    *(unsigned int*)(base + off)        = (unsigned)h0 | ((unsigned)h1 << 16);
    *(unsigned int*)(base + 8192 + off) = (unsigned)l0 | ((unsigned)l1 << 16);
  } else {                              // W2: g(28) x n2(32) x m(32) (m = kk-pair)
    int t2 = t - 57344;
    int g = t2 >> 10, rem = t2 & 1023, n2 = rem >> 5, m = rem & 31;
    int kk = 2*m;
    int ks = kk >> 5, qq = (kk >> 3) & 3, u = (kk >> 2) & 1, i = kk & 3;
    int kn = 32*ks + 16*u + 4*qq + i;   // kk and kk+1 -> kn and kn+1 (i in {0,2})
    float v0 = W2[(g*64 + kn    )*32 + n2];
    float v1 = W2[(g*64 + kn + 1)*32 + n2];
    unsigned short h0 = f2bf(v0), h1 = f2bf(v1);
    unsigned short l0 = f2bf(v0 - bf2f(h0)), l1 = f2bf(v1 - bf2f(h1));
    int off = (n2*128 + 4*m) ^ ((n2 & 7) << 4);
    unsigned char* base = ws + g*G_TILE_BYTES + 16384;
    *(unsigned int*)(base + off)        = (unsigned)h0 | ((unsigned)h1 << 16);
    *(unsigned int*)(base + 4096 + off) = (unsigned)l0 | ((unsigned)l1 << 16);
  }
}

// ---------------------------------------------------------------------------
// Main fused kernel. 1024 blocks x 256 threads (4 waves), 128 rows/block.
// Per g: weights staged block-cooperatively into LDS (double-buffered,
// global_load_lds width 16, T3 2-phase schedule). h1 never touches LDS:
// the W2 K-permutation makes layer-1 accumulators the layer-2 B-fragments.
// ---------------------------------------------------------------------------
__global__ __launch_bounds__(256, 2) void mlp_fused(
    const float* __restrict__ x,  const float* __restrict__ b1,
    const float* __restrict__ b2, const float* __restrict__ W3,
    const float* __restrict__ b3, const unsigned char* __restrict__ ws,
    float* __restrict__ out){
  // LDS: double-buffered weight tile (2 x 24 KiB) + output staging (14 KiB)
  __shared__ uint4 wbuf[2][1536];
  __shared__ float outb[128*28];

  const int tid = threadIdx.x;
  const int wv  = tid >> 6;
  const int ln  = tid & 63;
  const int l15 = ln & 15;
  const int q   = ln >> 4;
  const int rowBase = blockIdx.x * 128 + wv * 32;

  // ---- x B-fragments (bf16 hi/lo), loaded once, reused for all 28 g ----
  short8 xh[2][2], xl[2][2];
  #pragma unroll
  for (int rt = 0; rt < 2; ++rt)
    #pragma unroll
    for (int ks = 0; ks < 2; ++ks){
      const float* p = x + (rowBase + rt*16 + l15)*64 + ks*32 + q*8;
      f32x4 a = *(const f32x4*)p;
      f32x4 b = *(const f32x4*)(p + 4);
      short8 sh, sl;
      #pragma unroll
      for (int j = 0; j < 4; ++j){
        unsigned short h = f2bf(a[j]);
        sh[j]   = (short)h; sl[j]   = (short)f2bf(a[j] - bf2f(h));
        unsigned short h2 = f2bf(b[j]);
        sh[4+j] = (short)h2; sl[4+j] = (short)f2bf(b[j] - bf2f(h2));
      }
      xh[rt][ks] = sh; xl[rt][ks] = sl;
    }

  // ---- staging helper: wave wv copies its 6 KiB slice of g's 24 KiB tile ----
  auto stage = [&](int g, int buf){
    const unsigned char* gb = ws + g*G_TILE_BYTES + wv*6144 + ln*16;
    uint4* lb = &wbuf[buf][wv*384];
    #pragma unroll
    for (int it = 0; it < 6; ++it){
      __builtin_amdgcn_global_load_lds(
          (const __attribute__((address_space(1))) void*)(gb + it*1024),
          (__attribute__((address_space(3))) void*)(lb + it*64), 16, 0, 0);
    }
  };

  // prologue: stage g=0 into buf 0
  stage(0, 0);
  asm volatile("s_waitcnt vmcnt(0)" ::: "memory");
  __syncthreads();

  for (int g = 0; g < GN; ++g){
    const int cur = g & 1;
    if (g + 1 < GN) stage(g + 1, cur ^ 1);   // overlap next-g staging with compute
    const uint4* wb = wbuf[cur];

    // ---------------- layer 1: h1T[n=64][r=32/wave] ----------------
    short8 a1h[4][2], a1l[4][2];
    #pragma unroll
    for (int nt = 0; nt < 4; ++nt)
      #pragma unroll
      for (int ks = 0; ks < 2; ++ks){
        int n = nt*16 + l15;
        int off = ((n*128 + ks*64 + q*16) ^ ((n & 7) << 4)) >> 4;
        a1h[nt][ks] = __builtin_bit_cast(short8, wb[off]);
        a1l[nt][ks] = __builtin_bit_cast(short8, wb[512 + off]);
      }
    f32x4 acc1[4][2];
    #pragma unroll
    for (int nt = 0; nt < 4; ++nt){
      f32x4 bias = *(const f32x4*)(b1 + g*64 + nt*16 + q*4);
      acc1[nt][0] = bias; acc1[nt][1] = bias;
    }
    #pragma unroll
    for (int nt = 0; nt < 4; ++nt)
      #pragma unroll
      for (int rt = 0; rt < 2; ++rt)
        #pragma unroll
        for (int ks = 0; ks < 2; ++ks){
          acc1[nt][rt] = mfma16(a1h[nt][ks], xh[rt][ks], acc1[nt][rt]);
          acc1[nt][rt] = mfma16(a1h[nt][ks], xl[rt][ks], acc1[nt][rt]);
          acc1[nt][rt] = mfma16(a1l[nt][ks], xh[rt][ks], acc1[nt][rt]);
        }

    // ---- h1 relu + hi/lo split, packed IN REGISTERS as layer-2 B-frags ----
    // k-slot (ks, q*8+u*4+i) carries n = 32ks+16u+4q+i == acc1[2ks+u][rt][i]
    short8 bh[2][2], bl[2][2];
    #pragma unroll
    for (int rt = 0; rt < 2; ++rt)
      #pragma unroll
      for (int ks = 0; ks < 2; ++ks){
        f32x4 v0 = acc1[2*ks][rt], v1 = acc1[2*ks + 1][rt];
        short8 h, l;
        #pragma unroll
        for (int i = 0; i < 4; ++i){
          float a = fmaxf(v0[i], 0.0f);
          unsigned short ha = f2bf(a);
          h[i]   = (short)ha; l[i]   = (short)f2bf(a - bf2f(ha));
          float b = fmaxf(v1[i], 0.0f);
          unsigned short hb = f2bf(b);
          h[4+i] = (short)hb; l[4+i] = (short)f2bf(b - bf2f(hb));
        }
        bh[rt][ks] = h; bl[rt][ks] = l;
      }

    // ---------------- layer 2: h2T[n2=32][r=32/wave] ----------------
    short8 a2h[2][2], a2l[2][2];
    #pragma unroll
    for (int nt = 0; nt < 2; ++nt)
      #pragma unroll
      for (int ks = 0; ks < 2; ++ks){
        int n2 = nt*16 + l15;
        int off = ((n2*128 + ks*64 + q*16) ^ ((n2 & 7) << 4)) >> 4;
        a2h[nt][ks] = __builtin_bit_cast(short8, wb[1024 + off]);
        a2l[nt][ks] = __builtin_bit_cast(short8, wb[1280 + off]);
      }
    f32x4 acc2[2][2];
    #pragma unroll
    for (int nt = 0; nt < 2; ++nt){
      f32x4 bias = *(const f32x4*)(b2 + g*32 + nt*16 + q*4);
      acc2[nt][0] = bias; acc2[nt][1] = bias;
    }
    #pragma unroll
    for (int nt = 0; nt < 2; ++nt)
      #pragma unroll
      for (int rt = 0; rt < 2; ++rt)
        #pragma unroll
        for (int ks = 0; ks < 2; ++ks){
          acc2[nt][rt] = mfma16(a2h[nt][ks], bh[rt][ks], acc2[nt][rt]);
          acc2[nt][rt] = mfma16(a2h[nt][ks], bl[rt][ks], acc2[nt][rt]);
          acc2[nt][rt] = mfma16(a2l[nt][ks], bh[rt][ks], acc2[nt][rt]);
        }

    // ---------------- layer 3: in-register dot + quarter-reduce ----------------
    f32x4 w3f[2];
    #pragma unroll
    for (int nt = 0; nt < 2; ++nt)
      w3f[nt] = *(const f32x4*)(W3 + g*32 + nt*16 + q*4);
    float bias3 = b3[g];
    #pragma unroll
    for (int rt = 0; rt < 2; ++rt){
      float p = 0.0f;
      #pragma unroll
      for (int nt = 0; nt < 2; ++nt)
        #pragma unroll
        for (int i = 0; i < 4; ++i)
          p = fmaf(fmaxf(acc2[nt][rt][i], 0.0f), w3f[nt][i], p);
      p += __shfl_xor(p, 16);
      p += __shfl_xor(p, 32);
      p += bias3;
      if (ln < 16)
        outb[(wv*32 + rt*16 + ln)*28 + g] = p;
    }

    // drain this iteration's stage loads (they had the whole compute to land),
    // then barrier: everyone done reading buf[cur], buf[cur^1] fully staged.
    asm volatile("s_waitcnt vmcnt(0)" ::: "memory");
    __syncthreads();
  }

  // coalesced writeout: out is [B][28] row-major -> block chunk is contiguous
  const int ob = blockIdx.x * (128*28);
  #pragma unroll
  for (int j = 0; j < 14; ++j){
    int idx = j*256 + tid;
    out[ob + idx] = outb[idx];
  }
}

extern "C" void kernel_launch(void* const* d_in, const int* in_sizes, int n_in,
                              void* d_out, int out_size, void* d_ws, size_t ws_size,
                              hipStream_t stream){
  const float* x  = (const float*)d_in[0];
  const float* W1 = (const float*)d_in[1];
  const float* b1 = (const float*)d_in[2];
  const float* W2 = (const float*)d_in[3];
  const float* b2 = (const float*)d_in[4];
  const float* W3 = (const float*)d_in[5];
  const float* b3 = (const float*)d_in[6];
  unsigned char* ws = (unsigned char*)d_ws;
  float* out = (float*)d_out;
  if (ws_size < (size_t)WS_BYTES) return;
  hipLaunchKernelGGL(split_weights, dim3(336), dim3(256), 0, stream, W1, W2, ws);
  hipLaunchKernelGGL(mlp_fused, dim3(1024), dim3(256), 0, stream,
                     x, b1, b2, W3, b3, ws, out);
}

// Round 3
// 144.669 us; speedup vs baseline: 3.3862x; 1.4835x over previous
//
#include <hip/hip_runtime.h>
#include <hip/hip_bf16.h>
#include <hip/hip_fp16.h>

// Problem constants
#define GN 28
// ws layout: per-g contiguous 12288-byte tile, pre-swizzled for LDS staging:
//   [ W1 f16 [n=64][k=64] 8KiB | W2 f16 [n2=32][kk=64] K-permuted 4KiB ]
// byte = n*128 + 2k, XOR-swizzled ^((n&7)<<4)
#define G_TILE_BYTES 12288
#define WS_BYTES (GN * G_TILE_BYTES)   // 344064

typedef __attribute__((ext_vector_type(4))) float f32x4;
typedef __attribute__((ext_vector_type(8))) short short8;
typedef _Float16 f16x8 __attribute__((ext_vector_type(8)));

__device__ __forceinline__ unsigned short f2h(float v){
  __half h = __float2half(v);   // RNE
  return __builtin_bit_cast(unsigned short, h);
}
__device__ __forceinline__ f32x4 mfma16f(short8 a, short8 b, f32x4 c){
  return __builtin_amdgcn_mfma_f32_16x16x32_f16(
      __builtin_bit_cast(f16x8, a), __builtin_bit_cast(f16x8, b), c, 0, 0, 0);
}

// ---------------------------------------------------------------------------
// Prologue: fp32 weights -> f16, transposed, pre-swizzled, per-g 12 KiB tiles.
// W2 K-permuted so layer-1 D-fragments feed layer-2 B directly:
//   MFMA k-slot kk = ks*32 + q*8 + u*4 + i  carries  kn = 32*ks + 16*u + 4*q + i
// (mapping byte-identical to the round-2 hardware-verified kernel)
// ---------------------------------------------------------------------------
__global__ void split_weights(const float* __restrict__ W1,
                              const float* __restrict__ W2,
                              unsigned char* __restrict__ ws){
  int t = blockIdx.x * 256 + threadIdx.x;
  if (t < 57344){                       // W1: g(28) x n(64) x m(32)  (m = k-pair)
    int g = t >> 11, rem = t & 2047, n = rem >> 5, m = rem & 31;
    float v0 = W1[(g*64 + 2*m    )*64 + n];
    float v1 = W1[(g*64 + 2*m + 1)*64 + n];
    int off = (n*128 + 4*m) ^ ((n & 7) << 4);
    unsigned char* base = ws + g*G_TILE_BYTES;
    *(unsigned int*)(base + off) = (unsigned)f2h(v0) | ((unsigned)f2h(v1) << 16);
  } else {                              // W2: g(28) x n2(32) x m(32) (m = kk-pair)
    int t2 = t - 57344;
    int g = t2 >> 10, rem = t2 & 1023, n2 = rem >> 5, m = rem & 31;
    int kk = 2*m;
    int ks = kk >> 5, qq = (kk >> 3) & 3, u = (kk >> 2) & 1, i = kk & 3;
    int kn = 32*ks + 16*u + 4*qq + i;   // kk,kk+1 -> kn,kn+1 (i in {0,2})
    float v0 = W2[(g*64 + kn    )*32 + n2];
    float v1 = W2[(g*64 + kn + 1)*32 + n2];
    int off = (n2*128 + 4*m) ^ ((n2 & 7) << 4);
    unsigned char* base = ws + g*G_TILE_BYTES + 8192;
    *(unsigned int*)(base + off) = (unsigned)f2h(v0) | ((unsigned)f2h(v1) << 16);
  }
}

// ---------------------------------------------------------------------------
// Main fused kernel. 512 blocks x 256 threads (4 waves), 256 rows/block,
// 64 rows/wave (rt=4) -> per-CU weight fragment re-reads halved vs 32-row
// waves. Weights double-buffer staged via global_load_lds; all biases+W3
// preloaded to LDS once; g-loop has zero global VMEM besides the 3 stage
// loads, so the per-g vmcnt(0)+barrier is exact.
// ---------------------------------------------------------------------------
__global__ __launch_bounds__(256, 2) void mlp_fused(
    const float* __restrict__ x,  const float* __restrict__ b1,
    const float* __restrict__ b2, const float* __restrict__ W3,
    const float* __restrict__ b3, const unsigned char* __restrict__ ws,
    float* __restrict__ out){
  __shared__ uint4 wbuf[2][768];        // 2 x 12 KiB weight tile
  __shared__ float outb[256*28];        // 28 KiB output staging
  __shared__ float biasL[3616];         // b1[1792] | b2[896] | W3[896] | b3[28]

  const int tid = threadIdx.x;
  const int wv  = tid >> 6;
  const int ln  = tid & 63;
  const int l15 = ln & 15;
  const int q   = ln >> 4;
  const int rowBase = blockIdx.x * 256 + wv * 64;

  // ---- one-time bias/W3 preload into LDS ----
  #pragma unroll
  for (int i = 0; i < 7; ++i) biasL[i*256 + tid] = b1[i*256 + tid];
  if (tid < 128){
    #pragma unroll
    for (int i = 0; i < 7; ++i){
      biasL[1792 + i*128 + tid] = b2[i*128 + tid];
      biasL[2688 + i*128 + tid] = W3[i*128 + tid];
    }
  }
  if (tid < 28) biasL[3584 + tid] = b3[tid];

  // ---- x B-fragments (f16), loaded once, reused for all 28 g ----
  short8 xf[4][2];
  #pragma unroll
  for (int rt = 0; rt < 4; ++rt)
    #pragma unroll
    for (int ks = 0; ks < 2; ++ks){
      const float* p = x + (rowBase + rt*16 + l15)*64 + ks*32 + q*8;
      f32x4 a = *(const f32x4*)p;
      f32x4 b = *(const f32x4*)(p + 4);
      short8 s;
      #pragma unroll
      for (int j = 0; j < 4; ++j){
        s[j]   = (short)f2h(a[j]);
        s[4+j] = (short)f2h(b[j]);
      }
      xf[rt][ks] = s;
    }

  // ---- staging: wave wv copies its 3 KiB slice of g's 12 KiB tile ----
  auto stage = [&](int g, int buf){
    const unsigned char* gb = ws + g*G_TILE_BYTES + wv*3072 + ln*16;
    uint4* lb = &wbuf[buf][wv*192];
    #pragma unroll
    for (int it = 0; it < 3; ++it){
      __builtin_amdgcn_global_load_lds(
          (const __attribute__((address_space(1))) void*)(gb + it*1024),
          (__attribute__((address_space(3))) void*)(lb + it*64), 16, 0, 0);
    }
  };

  stage(0, 0);
  asm volatile("s_waitcnt vmcnt(0)" ::: "memory");
  __syncthreads();

  for (int g = 0; g < GN; ++g){
    const int cur = g & 1;
    if (g + 1 < GN) stage(g + 1, cur ^ 1);
    const uint4* wb = wbuf[cur];

    // ---------------- layer 1: h1T[n=64][r=64/wave] ----------------
    short8 a1[4][2];
    #pragma unroll
    for (int nt = 0; nt < 4; ++nt)
      #pragma unroll
      for (int ks = 0; ks < 2; ++ks){
        int n = nt*16 + l15;
        int off = ((n*128 + ks*64 + q*16) ^ ((n & 7) << 4)) >> 4;
        a1[nt][ks] = __builtin_bit_cast(short8, wb[off]);
      }
    f32x4 acc1[4][4];
    #pragma unroll
    for (int nt = 0; nt < 4; ++nt){
      f32x4 bias = *(const f32x4*)&biasL[g*64 + nt*16 + q*4];
      #pragma unroll
      for (int rt = 0; rt < 4; ++rt) acc1[nt][rt] = bias;
    }
    #pragma unroll
    for (int nt = 0; nt < 4; ++nt)
      #pragma unroll
      for (int rt = 0; rt < 4; ++rt)
        #pragma unroll
        for (int ks = 0; ks < 2; ++ks)
          acc1[nt][rt] = mfma16f(a1[nt][ks], xf[rt][ks], acc1[nt][rt]);

    // ---- h1 relu -> f16, packed IN REGISTERS as layer-2 B-frags ----
    // k-slot (ks, q*8+u*4+i) carries n = 32ks+16u+4q+i == acc1[2ks+u][rt][i]
    short8 bh[4][2];
    #pragma unroll
    for (int rt = 0; rt < 4; ++rt)
      #pragma unroll
      for (int ks = 0; ks < 2; ++ks){
        f32x4 v0 = acc1[2*ks][rt], v1 = acc1[2*ks + 1][rt];
        short8 h;
        #pragma unroll
        for (int i = 0; i < 4; ++i){
          h[i]   = (short)f2h(fmaxf(v0[i], 0.0f));
          h[4+i] = (short)f2h(fmaxf(v1[i], 0.0f));
        }
        bh[rt][ks] = h;
      }

    // ---------------- layer 2: h2T[n2=32][r=64/wave] ----------------
    short8 a2[2][2];
    #pragma unroll
    for (int nt = 0; nt < 2; ++nt)
      #pragma unroll
      for (int ks = 0; ks < 2; ++ks){
        int n2 = nt*16 + l15;
        int off = ((n2*128 + ks*64 + q*16) ^ ((n2 & 7) << 4)) >> 4;
        a2[nt][ks] = __builtin_bit_cast(short8, wb[512 + off]);
      }
    f32x4 acc2[2][4];
    #pragma unroll
    for (int nt = 0; nt < 2; ++nt){
      f32x4 bias = *(const f32x4*)&biasL[1792 + g*32 + nt*16 + q*4];
      #pragma unroll
      for (int rt = 0; rt < 4; ++rt) acc2[nt][rt] = bias;
    }
    #pragma unroll
    for (int nt = 0; nt < 2; ++nt)
      #pragma unroll
      for (int rt = 0; rt < 4; ++rt)
        #pragma unroll
        for (int ks = 0; ks < 2; ++ks)
          acc2[nt][rt] = mfma16f(a2[nt][ks], bh[rt][ks], acc2[nt][rt]);

    // ---------------- layer 3: in-register dot + quarter-reduce ----------------
    f32x4 w3f[2];
    #pragma unroll
    for (int nt = 0; nt < 2; ++nt)
      w3f[nt] = *(const f32x4*)&biasL[2688 + g*32 + nt*16 + q*4];
    float bias3 = biasL[3584 + g];
    #pragma unroll
    for (int rt = 0; rt < 4; ++rt){
      float p = 0.0f;
      #pragma unroll
      for (int nt = 0; nt < 2; ++nt)
        #pragma unroll
        for (int i = 0; i < 4; ++i)
          p = fmaf(fmaxf(acc2[nt][rt][i], 0.0f), w3f[nt][i], p);
      p += __shfl_xor(p, 16);
      p += __shfl_xor(p, 32);
      p += bias3;
      if (ln < 16)
        outb[(wv*64 + rt*16 + ln)*28 + g] = p;
    }

    // drain stage loads (had the whole compute phase to land), then barrier
    asm volatile("s_waitcnt vmcnt(0)" ::: "memory");
    __syncthreads();
  }

  // coalesced writeout: out is [B][28] row-major -> block chunk is contiguous
  const int ob = blockIdx.x * (256*28);
  #pragma unroll
  for (int j = 0; j < 28; ++j){
    int idx = j*256 + tid;
    out[ob + idx] = outb[idx];
  }
}

extern "C" void kernel_launch(void* const* d_in, const int* in_sizes, int n_in,
                              void* d_out, int out_size, void* d_ws, size_t ws_size,
                              hipStream_t stream){
  const float* x  = (const float*)d_in[0];
  const float* W1 = (const float*)d_in[1];
  const float* b1 = (const float*)d_in[2];
  const float* W2 = (const float*)d_in[3];
  const float* b2 = (const float*)d_in[4];
  const float* W3 = (const float*)d_in[5];
  const float* b3 = (const float*)d_in[6];
  unsigned char* ws = (unsigned char*)d_ws;
  float* out = (float*)d_out;
  if (ws_size < (size_t)WS_BYTES) return;
  hipLaunchKernelGGL(split_weights, dim3(336), dim3(256), 0, stream, W1, W2, ws);
  hipLaunchKernelGGL(mlp_fused, dim3(512), dim3(256), 0, stream,
                     x, b1, b2, W3, b3, ws, out);
}